// Round 5
// baseline (146.544 us; speedup 1.0000x reference)
//
#include <hip/hip_runtime.h>
#include <hip/hip_bf16.h>
#include <stdint.h>

typedef __attribute__((ext_vector_type(8))) short short8;
typedef __attribute__((ext_vector_type(4))) float f32x4;

#define BIGF 1e9f
#define NSLOT 64                 // col tiles = N/128
#define MAXM 96                  // max genuine members per pid (λ≈16, safe)

__device__ inline float blo(unsigned int u) {
    union { unsigned int i; float f; } v; v.i = u << 16; return v.f;
}
__device__ inline float bhi(unsigned int u) {
    union { unsigned int i; float f; } v; v.i = u & 0xffff0000u; return v.f;
}
__device__ inline unsigned int fkey(float s) {   // order-preserving uint encode
    unsigned int b = __float_as_uint(s);
    return (b & 0x80000000u) ? ~b : (b | 0x80000000u);
}
__device__ inline float funkey(unsigned int k) {
    unsigned int b = (k & 0x80000000u) ? (k & 0x7fffffffu) : ~k;
    return __uint_as_float(b);
}
__device__ inline void async16(const unsigned short* g, unsigned short* l) {
    __builtin_amdgcn_global_load_lds(
        (const __attribute__((address_space(1))) void*)g,
        (__attribute__((address_space(3))) void*)l, 16, 0, 0);
}
__device__ inline unsigned short f2b(float x) {
    __hip_bfloat16 h = __float2bfloat16(x);
    return *reinterpret_cast<unsigned short*>(&h);
}

// ---------------------------------------------------------------------------
// Kernel 1 (FUSED): blocks 0..255 = hardest-positive path (LONG POLES FIRST:
// they dispatch before the 2048 short normalize blocks so their latency
// overlaps the normalize flood); blocks 256..2303 = normalize path (4 rows
// each, exact round-2 math). hp path self-normalizes member rows from raw emb
// with the SAME op order -> bit-identical bf16 -> bit-identical hp.
// hp[] write partition: normalize path writes label!=1 rows (BIGF), hp path
// writes all label==1 rows (incl. sentinel). No cross-block dependency.
// ---------------------------------------------------------------------------
__global__ __launch_bounds__(256) void k_prep(
    const float* __restrict__ emb, const int* __restrict__ labels,
    const int* __restrict__ pids, unsigned short* __restrict__ normed,
    int* __restrict__ pg, float* __restrict__ hp,
    float* __restrict__ gred, int* __restrict__ done, int N)
{
    __shared__ int list[MAXM];
    __shared__ unsigned int hp_loc[MAXM];
    __shared__ unsigned short rows[MAXM * 256];   // 48 KB
    __shared__ int cnt;

    const int bid = blockIdx.x;
    const int t = threadIdx.x;
    const int w = t >> 6, lane = t & 63;

    if (bid == 0 && t < 3) {                 // zero reduction scratch
        if (t < 2) gred[t] = 0.f;
        else *done = 0;
    }

    if (bid >= 256) {
        // ---------------- normalize path (round-2 k_normalize, verbatim) ----
        int row = (bid - 256) * 4 + w;
        const float4* src = (const float4*)(emb + ((size_t)row << 8));
        float4 x = src[lane];
        float ss = x.x * x.x + x.y * x.y + x.z * x.z + x.w * x.w;
        #pragma unroll
        for (int off = 32; off >= 1; off >>= 1) ss += __shfl_xor(ss, off, 64);
        float inv = 1.0f / fmaxf(sqrtf(ss), 1e-12f);
        ushort4 o;
        o.x = f2b(x.x * inv); o.y = f2b(x.y * inv);
        o.z = f2b(x.z * inv); o.w = f2b(x.w * inv);
        ((ushort4*)(normed + ((size_t)row << 8)))[lane] = o;
        if (lane == 0) {
            int g = (labels[row] == 1) ? pids[row] : -1;
            pg[row] = (pids[row] & 0xffff) | ((g + 1) << 16);
            if (labels[row] != 1) hp[row] = BIGF;   // hp path owns label==1 rows
        }
        return;
    }

    // ---------------- hardest-positive path --------------------------------
    const int p = bid;
    if (t == 0) cnt = 0;
    __syncthreads();
    for (int j = t; j < N; j += 256)
        if (pids[j] == p && labels[j] == 1) {
            int idx = atomicAdd(&cnt, 1);
            if (idx < MAXM) list[idx] = j;
        }
    __syncthreads();
    int M = min(cnt, MAXM);
    for (int s = t; s < M; s += 256) hp_loc[s] = 0xFFFFFFFFu;
    // self-normalizing stage: one wave per member row, exact k_normalize math
    for (int s = w; s < M; s += 4) {
        const int row = list[s];
        const float4* src = (const float4*)(emb + ((size_t)row << 8));
        float4 x = src[lane];
        float ss = x.x * x.x + x.y * x.y + x.z * x.z + x.w * x.w;
        #pragma unroll
        for (int off = 32; off >= 1; off >>= 1) ss += __shfl_xor(ss, off, 64);
        float inv = 1.0f / fmaxf(sqrtf(ss), 1e-12f);
        ushort4 o;
        o.x = f2b(x.x * inv); o.y = f2b(x.y * inv);
        o.z = f2b(x.z * inv); o.w = f2b(x.w * inv);
        ((ushort4*)&rows[s * 256])[lane] = o;
    }
    __syncthreads();
    for (int pr = t; pr < M * M; pr += 256) {
        int i = pr / M, j = pr - i * M;
        if (i == j) continue;
        const uint4* ap = (const uint4*)&rows[i * 256];
        const uint4* bp = (const uint4*)&rows[j * 256];
        float s = 0.f;
        #pragma unroll 4
        for (int k = 0; k < 32; ++k) {
            uint4 a = ap[k], b = bp[k];
            s += blo(a.x) * blo(b.x) + bhi(a.x) * bhi(b.x);
            s += blo(a.y) * blo(b.y) + bhi(a.y) * bhi(b.y);
            s += blo(a.z) * blo(b.z) + bhi(a.z) * bhi(b.z);
            s += blo(a.w) * blo(b.w) + bhi(a.w) * bhi(b.w);
        }
        atomicMin(&hp_loc[i], fkey(s));
    }
    __syncthreads();
    for (int s = t; s < M; s += 256) {
        unsigned int key = hp_loc[s];
        hp[list[s]] = (key == 0xFFFFFFFFu) ? BIGF : funkey(key);
    }
}

// ---------------------------------------------------------------------------
// Kernel 2: symmetric MFMA pass (round-2 verified version, verbatim).
// 8 waves / 512 threads, 32x64 sub-tile per wave (acc[2][4] = 32 AGPR),
// double-buffered async staging, XOR-swizzled LDS, dual epilogue; diagonal
// (half-cost) tiles at the end of the grid. Partials via plain stores
// (round-3 lesson: device-scope atomic+fence tails stall the machine).
// ---------------------------------------------------------------------------
__global__ __launch_bounds__(512) void k_pass2(
    const unsigned short* __restrict__ normed, const int* __restrict__ pg,
    const float* __restrict__ hp,
    float* __restrict__ p_hnall, float* __restrict__ p_mbel, int N)
{
    const int b = blockIdx.x;
    int rt, ct;
    if (b >= 2016) {
        rt = b - 2016; ct = rt;
    } else {
        int r = (int)floorf((127.0f - sqrtf(16129.0f - 8.0f * (float)b)) * 0.5f);
        r = max(0, min(r, 62));
        while (63 * (r + 1) - ((r + 1) * r) / 2 <= b) ++r;   // fix float edge
        while (63 * r - (r * (r - 1)) / 2 > b) --r;
        rt = r;
        ct = r + 1 + (b - (63 * r - (r * (r - 1)) / 2));
    }
    const bool diag = (ct == rt);

    __shared__ unsigned short As[2][128 * 32];    // 16 KB
    __shared__ unsigned short Bs[2][128 * 32];    // 16 KB
    __shared__ float hp_r[128], hp_c[128];
    __shared__ int pg_r[128], pg_c[128];          // pid | (gpid+1)<<16
    __shared__ unsigned int red1[128], red2[128], red3[128], red4[128];

    const int t = threadIdx.x;          // 0..511
    const int lane = t & 63;
    const int w = t >> 6;               // 0..7
    const int wr = w & 3, wc = w >> 2;  // rows: wr*32.., cols: wc*64..
    const int quad = lane >> 4, l16 = lane & 15;
    const int rbase = rt * 128, cbase = ct * 128;

    if (t < 128) {
        hp_r[t] = hp[rbase + t];
        pg_r[t] = pg[rbase + t];
        hp_c[t] = hp[cbase + t];
        pg_c[t] = pg[cbase + t];
        red1[t] = 0u; red2[t] = 0u; red3[t] = 0u; red4[t] = 0u;
    }

    // staging: 512 threads x one 16B chunk each per tile per k-step.
    // row = t>>2, pos = t&3; LDS pos holds global chunk c = pos ^ ((row>>1)&3).
    const int r0 = t >> 2, p0 = t & 3;
    const int c0 = p0 ^ ((r0 >> 1) & 3);
    const unsigned short* gA = normed + ((size_t)(rbase + r0) << 8) + c0 * 8;
    const unsigned short* gB = normed + ((size_t)(cbase + r0) << 8) + c0 * 8;

    async16(gA, &As[0][t * 8]);
    if (!diag) async16(gB, &Bs[0][t * 8]);

    f32x4 acc[2][4];
    #pragma unroll
    for (int mt = 0; mt < 2; ++mt)
        #pragma unroll
        for (int nt = 0; nt < 4; ++nt)
            acc[mt][nt] = (f32x4){0.f, 0.f, 0.f, 0.f};

    const int sw = (l16 >> 1) & 3;
    const int aoff = (wr * 32 + l16) * 32 + (quad ^ sw) * 8;   // + mt*512
    const int boff = (wc * 64 + l16) * 32 + (quad ^ sw) * 8;   // + nt*512
    const unsigned short* Bbase[2] = { diag ? &As[0][0] : &Bs[0][0],
                                       diag ? &As[1][0] : &Bs[1][0] };

    for (int kb = 0; kb < 8; ++kb) {
        __syncthreads();                 // implicit vmcnt(0): stage kb landed
        int cur = kb & 1;
        if (kb < 7) {
            int nxt = cur ^ 1;
            int ko = (kb + 1) << 5;
            async16(gA + ko, &As[nxt][t * 8]);
            if (!diag) async16(gB + ko, &Bs[nxt][t * 8]);
        }
        short8 af[2], bf[4];
        #pragma unroll
        for (int mt = 0; mt < 2; ++mt)
            af[mt] = *reinterpret_cast<const short8*>(&As[cur][aoff + mt * 512]);
        #pragma unroll
        for (int nt = 0; nt < 4; ++nt)
            bf[nt] = *reinterpret_cast<const short8*>(&Bbase[cur][boff + nt * 512]);
        #pragma unroll
        for (int mt = 0; mt < 2; ++mt)
            #pragma unroll
            for (int nt = 0; nt < 4; ++nt)
                acc[mt][nt] = __builtin_amdgcn_mfma_f32_16x16x32_bf16(
                    af[mt], bf[nt], acc[mt][nt], 0, 0, 0);
    }

    // ---- normal epilogue: anchors = rows of rbase, candidates = cols ----
    // C layout: row = wr*32 + mt*16 + quad*4 + r, col = wc*64 + nt*16 + l16
    {
        const unsigned int gp0 = ((unsigned int)pg_c[wc * 64 +  0 + l16]) >> 16;
        const unsigned int gp1 = ((unsigned int)pg_c[wc * 64 + 16 + l16]) >> 16;
        const unsigned int gp2 = ((unsigned int)pg_c[wc * 64 + 32 + l16]) >> 16;
        const unsigned int gp3 = ((unsigned int)pg_c[wc * 64 + 48 + l16]) >> 16;
        #pragma unroll
        for (int mt = 0; mt < 2; ++mt) {
            #pragma unroll
            for (int r = 0; r < 4; ++r) {
                const int rl = wr * 32 + mt * 16 + quad * 4 + r;
                const unsigned int prP1 = ((unsigned int)pg_r[rl] & 0xffffu) + 1u;
                const float hprow = hp_r[rl];
                float tt0 = (prP1 != gp0) ? acc[mt][0][r] : -BIGF;
                float tt1 = (prP1 != gp1) ? acc[mt][1][r] : -BIGF;
                float tt2 = (prP1 != gp2) ? acc[mt][2][r] : -BIGF;
                float tt3 = (prP1 != gp3) ? acc[mt][3][r] : -BIGF;
                float v1 = fmaxf(fmaxf(tt0, tt1), fmaxf(tt2, tt3));
                float u0 = (tt0 < hprow) ? tt0 : -BIGF;
                float u1 = (tt1 < hprow) ? tt1 : -BIGF;
                float u2 = (tt2 < hprow) ? tt2 : -BIGF;
                float u3 = (tt3 < hprow) ? tt3 : -BIGF;
                float v2 = fmaxf(fmaxf(u0, u1), fmaxf(u2, u3));
                #pragma unroll
                for (int off = 8; off >= 1; off >>= 1) {
                    v1 = fmaxf(v1, __shfl_xor(v1, off, 64));
                    v2 = fmaxf(v2, __shfl_xor(v2, off, 64));
                }
                if (l16 == 0) {
                    atomicMax(&red1[rl], fkey(v1));
                    atomicMax(&red2[rl], fkey(v2));
                }
            }
        }
    }

    // ---- transpose epilogue: anchors = cols of cbase, candidates = rows ----
    if (!diag) {
        #pragma unroll
        for (int nt = 0; nt < 4; ++nt) {
            const int c = wc * 64 + nt * 16 + l16;
            const unsigned int pcP1 = ((unsigned int)pg_c[c] & 0xffffu) + 1u;
            const float hpc = hp_c[c];
            float a1 = -BIGF, b1 = -BIGF;
            #pragma unroll
            for (int mt = 0; mt < 2; ++mt) {
                const int4 pr4 = *(const int4*)&pg_r[wr * 32 + mt * 16 + quad * 4];
                float tt0 = (pcP1 != (((unsigned int)pr4.x) >> 16)) ? acc[mt][nt][0] : -BIGF;
                float tt1 = (pcP1 != (((unsigned int)pr4.y) >> 16)) ? acc[mt][nt][1] : -BIGF;
                float tt2 = (pcP1 != (((unsigned int)pr4.z) >> 16)) ? acc[mt][nt][2] : -BIGF;
                float tt3 = (pcP1 != (((unsigned int)pr4.w) >> 16)) ? acc[mt][nt][3] : -BIGF;
                a1 = fmaxf(a1, fmaxf(fmaxf(tt0, tt1), fmaxf(tt2, tt3)));
                float u0 = (tt0 < hpc) ? tt0 : -BIGF;
                float u1 = (tt1 < hpc) ? tt1 : -BIGF;
                float u2 = (tt2 < hpc) ? tt2 : -BIGF;
                float u3 = (tt3 < hpc) ? tt3 : -BIGF;
                b1 = fmaxf(b1, fmaxf(fmaxf(u0, u1), fmaxf(u2, u3)));
            }
            a1 = fmaxf(a1, __shfl_xor(a1, 16, 64));
            b1 = fmaxf(b1, __shfl_xor(b1, 16, 64));
            a1 = fmaxf(a1, __shfl_xor(a1, 32, 64));
            b1 = fmaxf(b1, __shfl_xor(b1, 32, 64));
            if (quad == 0) {                   // 16 lanes -> 16 distinct addrs
                atomicMax(&red3[c], fkey(a1));
                atomicMax(&red4[c], fkey(b1));
            }
        }
    }

    __syncthreads();
    if (t < 128) {
        p_hnall[(size_t)ct * N + rbase + t] = funkey(red1[t]);
        p_mbel[(size_t)ct * N + rbase + t] = funkey(red2[t]);
        if (!diag) {
            p_hnall[(size_t)rt * N + cbase + t] = funkey(red3[t]);
            p_mbel[(size_t)rt * N + cbase + t] = funkey(red4[t]);
        }
    }
}

// ---------------------------------------------------------------------------
// Kernel 3: per-row loss + grid reduce + fused final (last-block pattern).
// PARALLELISM FIX: 256 blocks (was 32 -> only 12.5% of CUs). Each block owns
// 32 rows; 8 threads per row each reduce 8 slots (coalesced: for a fixed
// slot, 32 consecutive lanes hit 32 consecutive rows), combined via
// shfl_xor(32) + tiny LDS transpose; wave 0 computes the 32 row losses.
// hn = (mbel > hp - margin) ? mbel : hn_all   (hn_cand == hn_all identity)
// ---------------------------------------------------------------------------
__global__ __launch_bounds__(256) void k_rowloss(
    const float* __restrict__ hp, const float* __restrict__ p_hnall,
    const float* __restrict__ p_mbel, const int* __restrict__ labels,
    float* __restrict__ gred, int* __restrict__ done,
    float* __restrict__ out, int N)
{
    const int t = threadIdx.x;
    const int r = blockIdx.x * 32 + (t & 31);    // row owned by this lane-group
    const int g = t >> 5;                        // slot-group 0..7 (8 slots each)
    float hn_all = -BIGF, mb = -BIGF;
    #pragma unroll
    for (int k = 0; k < 8; ++k) {
        const int s = g * 8 + k;
        hn_all = fmaxf(hn_all, p_hnall[(size_t)s * N + r]);
        mb     = fmaxf(mb,     p_mbel [(size_t)s * N + r]);
    }
    // combine the two slot-groups living in one wave (lanes l and l+32)
    hn_all = fmaxf(hn_all, __shfl_xor(hn_all, 32, 64));
    mb     = fmaxf(mb,     __shfl_xor(mb,     32, 64));
    __shared__ float shn[4][32], smb[4][32];
    const int w = t >> 6, l = t & 63;
    if (l < 32) { shn[w][l] = hn_all; smb[w][l] = mb; }
    __syncthreads();
    if (t < 32) {
        float hn1 = fmaxf(fmaxf(shn[0][t], shn[1][t]), fmaxf(shn[2][t], shn[3][t]));
        float mb1 = fmaxf(fmaxf(smb[0][t], smb[1][t]), fmaxf(smb[2][t], smb[3][t]));
        float hpv = hp[r];
        bool valid = (labels[r] == 1) && (hpv < 1e8f) && (hn1 > -1e8f);
        float hn = (mb1 > hpv - 0.5f) ? mb1 : hn1;
        float base = fmaxf(hn - hpv + 0.5f, 0.f);
        float wgt = (hpv < 0.6f || hn > 0.3f) ? 2.f : 1.f;
        float loss = base * wgt + 0.5f * (1.f - hpv) + 0.5f * fmaxf(hn + 0.2f, 0.f);
        float lsum = valid ? loss : 0.f;
        float lcnt = valid ? 1.f : 0.f;
        #pragma unroll
        for (int off = 16; off >= 1; off >>= 1) {   // lanes 0..31 only
            lsum += __shfl_xor(lsum, off, 64);
            lcnt += __shfl_xor(lcnt, off, 64);
        }
        if (t == 0) {
            atomicAdd(&gred[0], lsum);
            atomicAdd(&gred[1], lcnt);
            __threadfence();
            int old = atomicAdd(done, 1);
            if (old == (int)gridDim.x - 1) {
                float S = atomicAdd(&gred[0], 0.f);
                float C = atomicAdd(&gred[1], 0.f);
                out[0] = (C > 0.f) ? S / fmaxf(C, 1.f) : 0.f;
            }
        }
    }
}

extern "C" void kernel_launch(void* const* d_in, const int* in_sizes, int n_in,
                              void* d_out, int out_size, void* d_ws, size_t ws_size,
                              hipStream_t stream)
{
    const float* emb = (const float*)d_in[0];
    const int* labels = (const int*)d_in[1];
    const int* pids = (const int*)d_in[2];
    float* out = (float*)d_out;
    int N = in_sizes[1];          // 8192
    int D = in_sizes[0] / N;      // 256
    (void)D;

    char* ws = (char*)d_ws;
    unsigned short* normed = (unsigned short*)ws;  ws += (size_t)N * 256 * 2; // 4 MB bf16
    int* pg = (int*)ws;                            ws += (size_t)N * 4;
    float* hp = (float*)ws;                        ws += (size_t)N * 4;
    float* p_hnall = (float*)ws;                   ws += (size_t)N * NSLOT * 4;
    float* p_mbel = (float*)ws;                    ws += (size_t)N * NSLOT * 4;
    float* gred = (float*)ws;                      ws += 2 * 4;   // [sum, cnt]
    int* done = (int*)ws;                          ws += 4;

    int M = N / 128;                         // 64 tiles
    int tri = M * (M + 1) / 2;               // 2080 blocks (2016 offdiag + 64 diag)

    k_prep<<<256 + 2048, 256, 0, stream>>>(emb, labels, pids, normed, pg, hp,
                                           gred, done, N);
    k_pass2<<<tri, 512, 0, stream>>>(normed, pg, hp, p_hnall, p_mbel, N);
    k_rowloss<<<N / 32, 256, 0, stream>>>(hp, p_hnall, p_mbel, labels,
                                          gred, done, out, N);
}

// Round 7
// 131.657 us; speedup vs baseline: 1.1131x; 1.1131x over previous
//
#include <hip/hip_runtime.h>
#include <hip/hip_bf16.h>
#include <stdint.h>

typedef __attribute__((ext_vector_type(8))) short short8;
typedef __attribute__((ext_vector_type(4))) float f32x4;

#define BIGF 1e9f
#define NSLOT 64                 // col tiles = N/128
#define MAXM 96                  // max genuine members per pid (λ≈16, safe)

__device__ inline float blo(unsigned int u) {
    union { unsigned int i; float f; } v; v.i = u << 16; return v.f;
}
__device__ inline float bhi(unsigned int u) {
    union { unsigned int i; float f; } v; v.i = u & 0xffff0000u; return v.f;
}
__device__ inline unsigned int fkey(float s) {   // order-preserving uint encode
    unsigned int b = __float_as_uint(s);
    return (b & 0x80000000u) ? ~b : (b | 0x80000000u);
}
__device__ inline float funkey(unsigned int k) {
    unsigned int b = (k & 0x80000000u) ? (k & 0x7fffffffu) : ~k;
    return __uint_as_float(b);
}
__device__ inline void async16(const unsigned short* g, unsigned short* l) {
    __builtin_amdgcn_global_load_lds(
        (const __attribute__((address_space(1))) void*)g,
        (__attribute__((address_space(3))) void*)l, 16, 0, 0);
}
__device__ inline unsigned short f2b(float x) {
    __hip_bfloat16 h = __float2bfloat16(x);
    return *reinterpret_cast<unsigned short*>(&h);
}

// ---------------------------------------------------------------------------
// Kernel 1: L2-normalize rows (fp32), emit bf16 + packed (pid | (gpid+1)<<16),
// init hp sentinel. (R2-verified version.)
// ---------------------------------------------------------------------------
__global__ __launch_bounds__(256) void k_normalize(
    const float* __restrict__ emb, const int* __restrict__ labels,
    const int* __restrict__ pids, unsigned short* __restrict__ normed,
    int* __restrict__ pg, float* __restrict__ hp_init,
    float* __restrict__ gred, int* __restrict__ done)
{
    if (blockIdx.x == 0 && threadIdx.x < 3) {
        if (threadIdx.x < 2) gred[threadIdx.x] = 0.f;
        else *done = 0;
    }
    int w = threadIdx.x >> 6, lane = threadIdx.x & 63;
    int row = blockIdx.x * 4 + w;
    const float4* src = (const float4*)(emb + ((size_t)row << 8));
    float4 x = src[lane];
    float ss = x.x * x.x + x.y * x.y + x.z * x.z + x.w * x.w;
    #pragma unroll
    for (int off = 32; off >= 1; off >>= 1) ss += __shfl_xor(ss, off, 64);
    float inv = 1.0f / fmaxf(sqrtf(ss), 1e-12f);
    ushort4 o;
    o.x = f2b(x.x * inv); o.y = f2b(x.y * inv);
    o.z = f2b(x.z * inv); o.w = f2b(x.w * inv);
    ((ushort4*)(normed + ((size_t)row << 8)))[lane] = o;
    if (lane == 0) {
        int g = (labels[row] == 1) ? pids[row] : -1;
        pg[row] = (pids[row] & 0xffff) | ((g + 1) << 16);
        hp_init[row] = BIGF;
    }
}

// ---------------------------------------------------------------------------
// Kernel 2: hardest positive via per-pid groups (R2-verified version).
// ---------------------------------------------------------------------------
__global__ __launch_bounds__(256) void k_hp_pid(
    const unsigned short* __restrict__ normed, const int* __restrict__ labels,
    const int* __restrict__ pids, float* __restrict__ hp_out, int N, int D)
{
    __shared__ int list[MAXM];
    __shared__ unsigned int hp_loc[MAXM];
    __shared__ unsigned short rows[MAXM * 256];   // 48 KB
    __shared__ int cnt;
    int p = blockIdx.x;
    int t = threadIdx.x;
    if (t == 0) cnt = 0;
    __syncthreads();
    for (int j = t; j < N; j += 256)
        if (pids[j] == p && labels[j] == 1) {
            int idx = atomicAdd(&cnt, 1);
            if (idx < MAXM) list[idx] = j;
        }
    __syncthreads();
    int M = min(cnt, MAXM);
    for (int s = t; s < M; s += 256) hp_loc[s] = 0xFFFFFFFFu;
    for (int idx = t; idx < M * 32; idx += 256) {
        int mi = idx >> 5, ch = idx & 31;
        ((uint4*)&rows[mi * 256])[ch] =
            ((const uint4*)(normed + ((size_t)list[mi] << 8)))[ch];
    }
    __syncthreads();
    for (int pr = t; pr < M * M; pr += 256) {
        int i = pr / M, j = pr - i * M;
        if (i == j) continue;
        const uint4* ap = (const uint4*)&rows[i * 256];
        const uint4* bp = (const uint4*)&rows[j * 256];
        float s = 0.f;
        #pragma unroll 4
        for (int k = 0; k < 32; ++k) {
            uint4 a = ap[k], b = bp[k];
            s += blo(a.x) * blo(b.x) + bhi(a.x) * bhi(b.x);
            s += blo(a.y) * blo(b.y) + bhi(a.y) * bhi(b.y);
            s += blo(a.z) * blo(b.z) + bhi(a.z) * bhi(b.z);
            s += blo(a.w) * blo(b.w) + bhi(a.w) * bhi(b.w);
        }
        atomicMin(&hp_loc[i], fkey(s));
    }
    __syncthreads();
    for (int s = t; s < M; s += 256) {
        unsigned int key = hp_loc[s];
        hp_out[list[s]] = (key == 0xFFFFFFFFu) ? BIGF : funkey(key);
    }
}

// ---------------------------------------------------------------------------
// Kernel 3: symmetric MFMA pass. K-loop identical to the R2-verified version.
// Two-phase LDS-reduction epilogue (round-6 design, FIXED):
//   normal:   part[128][33]  — 32 partials/row  (wc x l16), 4 thr/row read 8.
//   transpose: tpart[128][17] — 16 partials/col (wr x quad), 4 thr/col read 4.
//   (R6 bug: tpart was [9] with index wr*4+quad in [0,16) -> OOB + half the
//    partials unread. 16 contributors, not 8.)
// ---------------------------------------------------------------------------
__global__ __launch_bounds__(512) void k_pass2(
    const unsigned short* __restrict__ normed, const int* __restrict__ pg,
    const float* __restrict__ hp,
    float* __restrict__ p_hnall, float* __restrict__ p_mbel, int N)
{
    const int b = blockIdx.x;
    int rt, ct;
    if (b >= 2016) {
        rt = b - 2016; ct = rt;
    } else {
        int r = (int)floorf((127.0f - sqrtf(16129.0f - 8.0f * (float)b)) * 0.5f);
        r = max(0, min(r, 62));
        while (63 * (r + 1) - ((r + 1) * r) / 2 <= b) ++r;   // fix float edge
        while (63 * r - (r * (r - 1)) / 2 > b) --r;
        rt = r;
        ct = r + 1 + (b - (63 * r - (r * (r - 1)) / 2));
    }
    const bool diag = (ct == rt);

    // union region: K-loop As[2]|Bs[2] (32 KB); epilogue part[128][33] float2
    // (33792 B) then tpart[128][17] float2 (17408 B).
    __shared__ __align__(16) unsigned char smem[33792];
    unsigned short (*As)[4096] = (unsigned short (*)[4096])(smem);          // 2x8KB
    unsigned short (*Bs)[4096] = (unsigned short (*)[4096])(smem + 16384);  // 2x8KB
    __shared__ float hp_r[128], hp_c[128];
    __shared__ int pg_r[128], pg_c[128];          // pid | (gpid+1)<<16

    const int t = threadIdx.x;          // 0..511
    const int lane = t & 63;
    const int w = t >> 6;               // 0..7
    const int wr = w & 3, wc = w >> 2;  // rows: wr*32.., cols: wc*64..
    const int quad = lane >> 4, l16 = lane & 15;
    const int rbase = rt * 128, cbase = ct * 128;

    if (t < 128) {
        hp_r[t] = hp[rbase + t];
        pg_r[t] = pg[rbase + t];
        hp_c[t] = hp[cbase + t];
        pg_c[t] = pg[cbase + t];
    }

    // staging: 512 threads x one 16B chunk each per tile per k-step.
    // row = t>>2, pos = t&3; LDS pos holds global chunk c = pos ^ ((row>>1)&3).
    const int r0 = t >> 2, p0 = t & 3;
    const int c0 = p0 ^ ((r0 >> 1) & 3);
    const unsigned short* gA = normed + ((size_t)(rbase + r0) << 8) + c0 * 8;
    const unsigned short* gB = normed + ((size_t)(cbase + r0) << 8) + c0 * 8;

    async16(gA, &As[0][t * 8]);
    if (!diag) async16(gB, &Bs[0][t * 8]);

    f32x4 acc[2][4];
    #pragma unroll
    for (int mt = 0; mt < 2; ++mt)
        #pragma unroll
        for (int nt = 0; nt < 4; ++nt)
            acc[mt][nt] = (f32x4){0.f, 0.f, 0.f, 0.f};

    const int sw = (l16 >> 1) & 3;
    const int aoff = (wr * 32 + l16) * 32 + (quad ^ sw) * 8;   // + mt*512
    const int boff = (wc * 64 + l16) * 32 + (quad ^ sw) * 8;   // + nt*512
    const unsigned short* Bbase[2] = { diag ? &As[0][0] : &Bs[0][0],
                                       diag ? &As[1][0] : &Bs[1][0] };

    for (int kb = 0; kb < 8; ++kb) {
        __syncthreads();                 // implicit vmcnt(0): stage kb landed
        int cur = kb & 1;
        if (kb < 7) {
            int nxt = cur ^ 1;
            int ko = (kb + 1) << 5;
            async16(gA + ko, &As[nxt][t * 8]);
            if (!diag) async16(gB + ko, &Bs[nxt][t * 8]);
        }
        short8 af[2], bf[4];
        #pragma unroll
        for (int mt = 0; mt < 2; ++mt)
            af[mt] = *reinterpret_cast<const short8*>(&As[cur][aoff + mt * 512]);
        #pragma unroll
        for (int nt = 0; nt < 4; ++nt)
            bf[nt] = *reinterpret_cast<const short8*>(&Bbase[cur][boff + nt * 512]);
        #pragma unroll
        for (int mt = 0; mt < 2; ++mt)
            #pragma unroll
            for (int nt = 0; nt < 4; ++nt)
                acc[mt][nt] = __builtin_amdgcn_mfma_f32_16x16x32_bf16(
                    af[mt], bf[nt], acc[mt][nt], 0, 0, 0);
    }

    __syncthreads();   // all waves done reading As/Bs -> region reusable

    // ---- normal epilogue, phase 1: nt-fold + partial store ----
    // C layout: row = wr*32 + mt*16 + quad*4 + r, col = wc*64 + nt*16 + l16
    float2 (*part)[33] = (float2 (*)[33])smem;     // [row][wc*16+l16], +1 pad
    {
        const int cs = wc * 16 + l16;
        const unsigned int gp0 = ((unsigned int)pg_c[wc * 64 +  0 + l16]) >> 16;
        const unsigned int gp1 = ((unsigned int)pg_c[wc * 64 + 16 + l16]) >> 16;
        const unsigned int gp2 = ((unsigned int)pg_c[wc * 64 + 32 + l16]) >> 16;
        const unsigned int gp3 = ((unsigned int)pg_c[wc * 64 + 48 + l16]) >> 16;
        #pragma unroll
        for (int mt = 0; mt < 2; ++mt) {
            #pragma unroll
            for (int r = 0; r < 4; ++r) {
                const int rl = wr * 32 + mt * 16 + quad * 4 + r;
                const unsigned int prP1 = ((unsigned int)pg_r[rl] & 0xffffu) + 1u;
                const float hprow = hp_r[rl];
                float tt0 = (prP1 != gp0) ? acc[mt][0][r] : -BIGF;
                float tt1 = (prP1 != gp1) ? acc[mt][1][r] : -BIGF;
                float tt2 = (prP1 != gp2) ? acc[mt][2][r] : -BIGF;
                float tt3 = (prP1 != gp3) ? acc[mt][3][r] : -BIGF;
                float v1 = fmaxf(fmaxf(tt0, tt1), fmaxf(tt2, tt3));
                float u0 = (tt0 < hprow) ? tt0 : -BIGF;
                float u1 = (tt1 < hprow) ? tt1 : -BIGF;
                float u2 = (tt2 < hprow) ? tt2 : -BIGF;
                float u3 = (tt3 < hprow) ? tt3 : -BIGF;
                float v2 = fmaxf(fmaxf(u0, u1), fmaxf(u2, u3));
                part[rl][cs] = float2{v1, v2};
            }
        }
    }
    __syncthreads();

    // ---- normal epilogue, phase 2: 4 threads/row reduce 32 partials ----
    {
        const int row = t >> 2, seg = t & 3;
        float v1 = -BIGF, v2 = -BIGF;
        #pragma unroll
        for (int k = 0; k < 8; ++k) {
            float2 p = part[row][seg * 8 + k];
            v1 = fmaxf(v1, p.x); v2 = fmaxf(v2, p.y);
        }
        v1 = fmaxf(v1, __shfl_xor(v1, 1, 64));
        v2 = fmaxf(v2, __shfl_xor(v2, 1, 64));
        v1 = fmaxf(v1, __shfl_xor(v1, 2, 64));
        v2 = fmaxf(v2, __shfl_xor(v2, 2, 64));
        if (seg == 0) {
            p_hnall[(size_t)ct * N + rbase + row] = v1;
            p_mbel [(size_t)ct * N + rbase + row] = v2;
        }
    }

    // ---- transpose epilogue (off-diag): same two-phase scheme, 16 partials --
    if (!diag) {
        __syncthreads();               // protect part[] until phase 2 done
        float2 (*tpart)[17] = (float2 (*)[17])smem;   // [col][wr*4+quad], +1 pad
        #pragma unroll
        for (int nt = 0; nt < 4; ++nt) {
            const int c = wc * 64 + nt * 16 + l16;
            const unsigned int pcP1 = ((unsigned int)pg_c[c] & 0xffffu) + 1u;
            const float hpc = hp_c[c];
            float a1 = -BIGF, b1 = -BIGF;
            #pragma unroll
            for (int mt = 0; mt < 2; ++mt) {
                const int4 pr4 = *(const int4*)&pg_r[wr * 32 + mt * 16 + quad * 4];
                float tt0 = (pcP1 != (((unsigned int)pr4.x) >> 16)) ? acc[mt][nt][0] : -BIGF;
                float tt1 = (pcP1 != (((unsigned int)pr4.y) >> 16)) ? acc[mt][nt][1] : -BIGF;
                float tt2 = (pcP1 != (((unsigned int)pr4.z) >> 16)) ? acc[mt][nt][2] : -BIGF;
                float tt3 = (pcP1 != (((unsigned int)pr4.w) >> 16)) ? acc[mt][nt][3] : -BIGF;
                a1 = fmaxf(a1, fmaxf(fmaxf(tt0, tt1), fmaxf(tt2, tt3)));
                float u0 = (tt0 < hpc) ? tt0 : -BIGF;
                float u1 = (tt1 < hpc) ? tt1 : -BIGF;
                float u2 = (tt2 < hpc) ? tt2 : -BIGF;
                float u3 = (tt3 < hpc) ? tt3 : -BIGF;
                b1 = fmaxf(b1, fmaxf(fmaxf(u0, u1), fmaxf(u2, u3)));
            }
            tpart[c][wr * 4 + quad] = float2{a1, b1};
        }
        __syncthreads();
        {
            const int c = t >> 2, sg = t & 3;
            float a = -BIGF, bm = -BIGF;
            #pragma unroll
            for (int k = 0; k < 4; ++k) {
                float2 p = tpart[c][sg * 4 + k];
                a = fmaxf(a, p.x); bm = fmaxf(bm, p.y);
            }
            a  = fmaxf(a,  __shfl_xor(a,  1, 64));
            bm = fmaxf(bm, __shfl_xor(bm, 1, 64));
            a  = fmaxf(a,  __shfl_xor(a,  2, 64));
            bm = fmaxf(bm, __shfl_xor(bm, 2, 64));
            if (sg == 0) {
                p_hnall[(size_t)rt * N + cbase + c] = a;
                p_mbel [(size_t)rt * N + cbase + c] = bm;
            }
        }
    }
}

// ---------------------------------------------------------------------------
// Kernel 4: per-row loss + grid reduce + fused final (parallel version:
// 256 blocks, 32 rows/block, coalesced slot-major reads).
// hn = (mbel > hp - margin) ? mbel : hn_all   (hn_cand == hn_all identity)
// ---------------------------------------------------------------------------
__global__ __launch_bounds__(256) void k_rowloss(
    const float* __restrict__ hp, const float* __restrict__ p_hnall,
    const float* __restrict__ p_mbel, const int* __restrict__ labels,
    float* __restrict__ gred, int* __restrict__ done,
    float* __restrict__ out, int N)
{
    const int t = threadIdx.x;
    const int r = blockIdx.x * 32 + (t & 31);    // row owned by this lane-group
    const int g = t >> 5;                        // slot-group 0..7 (8 slots each)
    float hn_all = -BIGF, mb = -BIGF;
    #pragma unroll
    for (int k = 0; k < 8; ++k) {
        const int s = g * 8 + k;
        hn_all = fmaxf(hn_all, p_hnall[(size_t)s * N + r]);
        mb     = fmaxf(mb,     p_mbel [(size_t)s * N + r]);
    }
    hn_all = fmaxf(hn_all, __shfl_xor(hn_all, 32, 64));
    mb     = fmaxf(mb,     __shfl_xor(mb,     32, 64));
    __shared__ float shn[4][32], smb[4][32];
    const int w = t >> 6, l = t & 63;
    if (l < 32) { shn[w][l] = hn_all; smb[w][l] = mb; }
    __syncthreads();
    if (t < 32) {
        float hn1 = fmaxf(fmaxf(shn[0][t], shn[1][t]), fmaxf(shn[2][t], shn[3][t]));
        float mb1 = fmaxf(fmaxf(smb[0][t], smb[1][t]), fmaxf(smb[2][t], smb[3][t]));
        float hpv = hp[r];
        bool valid = (labels[r] == 1) && (hpv < 1e8f) && (hn1 > -1e8f);
        float hn = (mb1 > hpv - 0.5f) ? mb1 : hn1;
        float base = fmaxf(hn - hpv + 0.5f, 0.f);
        float wgt = (hpv < 0.6f || hn > 0.3f) ? 2.f : 1.f;
        float loss = base * wgt + 0.5f * (1.f - hpv) + 0.5f * fmaxf(hn + 0.2f, 0.f);
        float lsum = valid ? loss : 0.f;
        float lcnt = valid ? 1.f : 0.f;
        #pragma unroll
        for (int off = 16; off >= 1; off >>= 1) {
            lsum += __shfl_xor(lsum, off, 64);
            lcnt += __shfl_xor(lcnt, off, 64);
        }
        if (t == 0) {
            atomicAdd(&gred[0], lsum);
            atomicAdd(&gred[1], lcnt);
            __threadfence();
            int old = atomicAdd(done, 1);
            if (old == (int)gridDim.x - 1) {
                float S = atomicAdd(&gred[0], 0.f);
                float C = atomicAdd(&gred[1], 0.f);
                out[0] = (C > 0.f) ? S / fmaxf(C, 1.f) : 0.f;
            }
        }
    }
}

extern "C" void kernel_launch(void* const* d_in, const int* in_sizes, int n_in,
                              void* d_out, int out_size, void* d_ws, size_t ws_size,
                              hipStream_t stream)
{
    const float* emb = (const float*)d_in[0];
    const int* labels = (const int*)d_in[1];
    const int* pids = (const int*)d_in[2];
    float* out = (float*)d_out;
    int N = in_sizes[1];          // 8192
    int D = in_sizes[0] / N;      // 256

    char* ws = (char*)d_ws;
    unsigned short* normed = (unsigned short*)ws;  ws += (size_t)N * D * 2;  // 4 MB bf16
    int* pg = (int*)ws;                            ws += (size_t)N * 4;
    float* hp = (float*)ws;                        ws += (size_t)N * 4;
    float* p_hnall = (float*)ws;                   ws += (size_t)N * NSLOT * 4;
    float* p_mbel = (float*)ws;                    ws += (size_t)N * NSLOT * 4;
    float* gred = (float*)ws;                      ws += 2 * 4;   // [sum, cnt]
    int* done = (int*)ws;                          ws += 4;

    int M = N / 128;                         // 64 tiles
    int tri = M * (M + 1) / 2;               // 2080 blocks (2016 offdiag + 64 diag)

    k_normalize<<<N / 4, 256, 0, stream>>>(emb, labels, pids, normed, pg, hp,
                                           gred, done);
    k_hp_pid<<<256, 256, 0, stream>>>(normed, labels, pids, hp, N, D);
    k_pass2<<<tri, 512, 0, stream>>>(normed, pg, hp, p_hnall, p_mbel, N);
    k_rowloss<<<N / 32, 256, 0, stream>>>(hp, p_hnall, p_mbel, labels,
                                          gred, done, out, N);
}

// Round 8
// 131.209 us; speedup vs baseline: 1.1169x; 1.0034x over previous
//
#include <hip/hip_runtime.h>
#include <hip/hip_bf16.h>
#include <stdint.h>

typedef __attribute__((ext_vector_type(8))) short short8;
typedef __attribute__((ext_vector_type(4))) float f32x4;

#define BIGF 1e9f
#define NSLOT 64                 // col tiles = N/128
#define MAXM 96                  // max genuine members per pid (λ≈16, safe)

__device__ inline float blo(unsigned int u) {
    union { unsigned int i; float f; } v; v.i = u << 16; return v.f;
}
__device__ inline float bhi(unsigned int u) {
    union { unsigned int i; float f; } v; v.i = u & 0xffff0000u; return v.f;
}
__device__ inline unsigned int fkey(float s) {   // order-preserving uint encode
    unsigned int b = __float_as_uint(s);
    return (b & 0x80000000u) ? ~b : (b | 0x80000000u);
}
__device__ inline float funkey(unsigned int k) {
    unsigned int b = (k & 0x80000000u) ? (k & 0x7fffffffu) : ~k;
    return __uint_as_float(b);
}
__device__ inline void async16(const unsigned short* g, unsigned short* l) {
    __builtin_amdgcn_global_load_lds(
        (const __attribute__((address_space(1))) void*)g,
        (__attribute__((address_space(3))) void*)l, 16, 0, 0);
}
__device__ inline unsigned short f2b(float x) {
    __hip_bfloat16 h = __float2bfloat16(x);
    return *reinterpret_cast<unsigned short*>(&h);
}

// ---------------------------------------------------------------------------
// Kernel 1: L2-normalize rows (fp32), emit bf16 + packed (pid | (gpid+1)<<16),
// init hp sentinel. (R2-verified version.)
// ---------------------------------------------------------------------------
__global__ __launch_bounds__(256) void k_normalize(
    const float* __restrict__ emb, const int* __restrict__ labels,
    const int* __restrict__ pids, unsigned short* __restrict__ normed,
    int* __restrict__ pg, float* __restrict__ hp_init,
    float* __restrict__ gred, int* __restrict__ done)
{
    if (blockIdx.x == 0 && threadIdx.x < 3) {
        if (threadIdx.x < 2) gred[threadIdx.x] = 0.f;
        else *done = 0;
    }
    int w = threadIdx.x >> 6, lane = threadIdx.x & 63;
    int row = blockIdx.x * 4 + w;
    const float4* src = (const float4*)(emb + ((size_t)row << 8));
    float4 x = src[lane];
    float ss = x.x * x.x + x.y * x.y + x.z * x.z + x.w * x.w;
    #pragma unroll
    for (int off = 32; off >= 1; off >>= 1) ss += __shfl_xor(ss, off, 64);
    float inv = 1.0f / fmaxf(sqrtf(ss), 1e-12f);
    ushort4 o;
    o.x = f2b(x.x * inv); o.y = f2b(x.y * inv);
    o.z = f2b(x.z * inv); o.w = f2b(x.w * inv);
    ((ushort4*)(normed + ((size_t)row << 8)))[lane] = o;
    if (lane == 0) {
        int g = (labels[row] == 1) ? pids[row] : -1;
        pg[row] = (pids[row] & 0xffff) | ((g + 1) << 16);
        hp_init[row] = BIGF;
    }
}

// ---------------------------------------------------------------------------
// Kernel 2: hardest positive via per-pid groups (R2-verified version).
// ---------------------------------------------------------------------------
__global__ __launch_bounds__(256) void k_hp_pid(
    const unsigned short* __restrict__ normed, const int* __restrict__ labels,
    const int* __restrict__ pids, float* __restrict__ hp_out, int N, int D)
{
    __shared__ int list[MAXM];
    __shared__ unsigned int hp_loc[MAXM];
    __shared__ unsigned short rows[MAXM * 256];   // 48 KB
    __shared__ int cnt;
    int p = blockIdx.x;
    int t = threadIdx.x;
    if (t == 0) cnt = 0;
    __syncthreads();
    for (int j = t; j < N; j += 256)
        if (pids[j] == p && labels[j] == 1) {
            int idx = atomicAdd(&cnt, 1);
            if (idx < MAXM) list[idx] = j;
        }
    __syncthreads();
    int M = min(cnt, MAXM);
    for (int s = t; s < M; s += 256) hp_loc[s] = 0xFFFFFFFFu;
    for (int idx = t; idx < M * 32; idx += 256) {
        int mi = idx >> 5, ch = idx & 31;
        ((uint4*)&rows[mi * 256])[ch] =
            ((const uint4*)(normed + ((size_t)list[mi] << 8)))[ch];
    }
    __syncthreads();
    for (int pr = t; pr < M * M; pr += 256) {
        int i = pr / M, j = pr - i * M;
        if (i == j) continue;
        const uint4* ap = (const uint4*)&rows[i * 256];
        const uint4* bp = (const uint4*)&rows[j * 256];
        float s = 0.f;
        #pragma unroll 4
        for (int k = 0; k < 32; ++k) {
            uint4 a = ap[k], b = bp[k];
            s += blo(a.x) * blo(b.x) + bhi(a.x) * bhi(b.x);
            s += blo(a.y) * blo(b.y) + bhi(a.y) * bhi(b.y);
            s += blo(a.z) * blo(b.z) + bhi(a.z) * bhi(b.z);
            s += blo(a.w) * blo(b.w) + bhi(a.w) * bhi(b.w);
        }
        atomicMin(&hp_loc[i], fkey(s));
    }
    __syncthreads();
    for (int s = t; s < M; s += 256) {
        unsigned int key = hp_loc[s];
        hp_out[list[s]] = (key == 0xFFFFFFFFu) ? BIGF : funkey(key);
    }
}

// ---------------------------------------------------------------------------
// Kernel 3: symmetric MFMA pass. R7-verified epilogue (two-phase LDS
// reduction). K-LOOP CHANGE (T3/T4-lite): 3-buffer, depth-2 prefetch with
// counted vmcnt + raw s_barrier — replaces __syncthreads()'s forced
// vmcnt(0) drain (one exposed load latency per k-step, the m97 stall).
//   prologue: stage 0,1 issued (4 loads/thread outstanding)
//   iter kb:  s_waitcnt vmcnt(2)  (stage kb landed; kb+1 stays in flight)
//             s_barrier
//             issue stage kb+2 (buffer (kb+2)%3, last read at kb-1 — all
//             waves passed this barrier after those reads: safe)
//             ds_read buf[kb%3] -> 8 MFMA
//   kb==7:    vmcnt(0) (last stage, nothing else in flight)
// Diag blocks now stage B too (uniform compile-time vmcnt counts; 64 blocks
// of redundant L2-hit loads = negligible).
// ---------------------------------------------------------------------------
__global__ __launch_bounds__(512) void k_pass2(
    const unsigned short* __restrict__ normed, const int* __restrict__ pg,
    const float* __restrict__ hp,
    float* __restrict__ p_hnall, float* __restrict__ p_mbel, int N)
{
    const int b = blockIdx.x;
    int rt, ct;
    if (b >= 2016) {
        rt = b - 2016; ct = rt;
    } else {
        int r = (int)floorf((127.0f - sqrtf(16129.0f - 8.0f * (float)b)) * 0.5f);
        r = max(0, min(r, 62));
        while (63 * (r + 1) - ((r + 1) * r) / 2 <= b) ++r;   // fix float edge
        while (63 * r - (r * (r - 1)) / 2 > b) --r;
        rt = r;
        ct = r + 1 + (b - (63 * r - (r * (r - 1)) / 2));
    }
    const bool diag = (ct == rt);

    // union region: K-loop As[3]|Bs[3] (48 KB); epilogue part[128][33] float2
    // (33792 B) then tpart[128][17] float2 (17408 B).
    __shared__ __align__(16) unsigned char smem[49152];
    unsigned short (*As)[4096] = (unsigned short (*)[4096])(smem);          // 3x8KB
    unsigned short (*Bs)[4096] = (unsigned short (*)[4096])(smem + 24576);  // 3x8KB
    __shared__ float hp_r[128], hp_c[128];
    __shared__ int pg_r[128], pg_c[128];          // pid | (gpid+1)<<16

    const int t = threadIdx.x;          // 0..511
    const int lane = t & 63;
    const int w = t >> 6;               // 0..7
    const int wr = w & 3, wc = w >> 2;  // rows: wr*32.., cols: wc*64..
    const int quad = lane >> 4, l16 = lane & 15;
    const int rbase = rt * 128, cbase = ct * 128;

    if (t < 128) {
        hp_r[t] = hp[rbase + t];
        pg_r[t] = pg[rbase + t];
        hp_c[t] = hp[cbase + t];
        pg_c[t] = pg[cbase + t];
    }

    // staging: 512 threads x one 16B chunk each per tile per k-step.
    // row = t>>2, pos = t&3; LDS pos holds global chunk c = pos ^ ((row>>1)&3).
    const int r0 = t >> 2, p0 = t & 3;
    const int c0 = p0 ^ ((r0 >> 1) & 3);
    const unsigned short* gA = normed + ((size_t)(rbase + r0) << 8) + c0 * 8;
    const unsigned short* gB = normed + ((size_t)(cbase + r0) << 8) + c0 * 8;

    // prologue: stages 0 and 1 in flight (A then B per stage: in-order vmcnt)
    async16(gA, &As[0][t * 8]);
    async16(gB, &Bs[0][t * 8]);
    async16(gA + 32, &As[1][t * 8]);
    async16(gB + 32, &Bs[1][t * 8]);

    f32x4 acc[2][4];
    #pragma unroll
    for (int mt = 0; mt < 2; ++mt)
        #pragma unroll
        for (int nt = 0; nt < 4; ++nt)
            acc[mt][nt] = (f32x4){0.f, 0.f, 0.f, 0.f};

    const int sw = (l16 >> 1) & 3;
    const int aoff = (wr * 32 + l16) * 32 + (quad ^ sw) * 8;   // + mt*512
    const int boff = (wc * 64 + l16) * 32 + (quad ^ sw) * 8;   // + nt*512

    #pragma unroll
    for (int kb = 0; kb < 8; ++kb) {
        // wait stage kb only (2 oldest loads); keep stage kb+1 in flight
        if (kb == 7) asm volatile("s_waitcnt vmcnt(0)" ::: "memory");
        else         asm volatile("s_waitcnt vmcnt(2)" ::: "memory");
        __builtin_amdgcn_s_barrier();
        if (kb < 6) {
            const int ko = (kb + 2) << 5;
            const int nxt = (kb + 2) % 3;
            async16(gA + ko, &As[nxt][t * 8]);
            async16(gB + ko, &Bs[nxt][t * 8]);
        }
        const int cur = kb % 3;
        short8 af[2], bf[4];
        #pragma unroll
        for (int mt = 0; mt < 2; ++mt)
            af[mt] = *reinterpret_cast<const short8*>(&As[cur][aoff + mt * 512]);
        #pragma unroll
        for (int nt = 0; nt < 4; ++nt)
            bf[nt] = *reinterpret_cast<const short8*>(&Bs[cur][boff + nt * 512]);
        #pragma unroll
        for (int mt = 0; mt < 2; ++mt)
            #pragma unroll
            for (int nt = 0; nt < 4; ++nt)
                acc[mt][nt] = __builtin_amdgcn_mfma_f32_16x16x32_bf16(
                    af[mt], bf[nt], acc[mt][nt], 0, 0, 0);
    }

    __syncthreads();   // all waves done reading As/Bs -> region reusable

    // ---- normal epilogue, phase 1: nt-fold + partial store ----
    // C layout: row = wr*32 + mt*16 + quad*4 + r, col = wc*64 + nt*16 + l16
    float2 (*part)[33] = (float2 (*)[33])smem;     // [row][wc*16+l16], +1 pad
    {
        const int cs = wc * 16 + l16;
        const unsigned int gp0 = ((unsigned int)pg_c[wc * 64 +  0 + l16]) >> 16;
        const unsigned int gp1 = ((unsigned int)pg_c[wc * 64 + 16 + l16]) >> 16;
        const unsigned int gp2 = ((unsigned int)pg_c[wc * 64 + 32 + l16]) >> 16;
        const unsigned int gp3 = ((unsigned int)pg_c[wc * 64 + 48 + l16]) >> 16;
        #pragma unroll
        for (int mt = 0; mt < 2; ++mt) {
            #pragma unroll
            for (int r = 0; r < 4; ++r) {
                const int rl = wr * 32 + mt * 16 + quad * 4 + r;
                const unsigned int prP1 = ((unsigned int)pg_r[rl] & 0xffffu) + 1u;
                const float hprow = hp_r[rl];
                float tt0 = (prP1 != gp0) ? acc[mt][0][r] : -BIGF;
                float tt1 = (prP1 != gp1) ? acc[mt][1][r] : -BIGF;
                float tt2 = (prP1 != gp2) ? acc[mt][2][r] : -BIGF;
                float tt3 = (prP1 != gp3) ? acc[mt][3][r] : -BIGF;
                float v1 = fmaxf(fmaxf(tt0, tt1), fmaxf(tt2, tt3));
                float u0 = (tt0 < hprow) ? tt0 : -BIGF;
                float u1 = (tt1 < hprow) ? tt1 : -BIGF;
                float u2 = (tt2 < hprow) ? tt2 : -BIGF;
                float u3 = (tt3 < hprow) ? tt3 : -BIGF;
                float v2 = fmaxf(fmaxf(u0, u1), fmaxf(u2, u3));
                part[rl][cs] = float2{v1, v2};
            }
        }
    }
    __syncthreads();

    // ---- normal epilogue, phase 2: 4 threads/row reduce 32 partials ----
    {
        const int row = t >> 2, seg = t & 3;
        float v1 = -BIGF, v2 = -BIGF;
        #pragma unroll
        for (int k = 0; k < 8; ++k) {
            float2 p = part[row][seg * 8 + k];
            v1 = fmaxf(v1, p.x); v2 = fmaxf(v2, p.y);
        }
        v1 = fmaxf(v1, __shfl_xor(v1, 1, 64));
        v2 = fmaxf(v2, __shfl_xor(v2, 1, 64));
        v1 = fmaxf(v1, __shfl_xor(v1, 2, 64));
        v2 = fmaxf(v2, __shfl_xor(v2, 2, 64));
        if (seg == 0) {
            p_hnall[(size_t)ct * N + rbase + row] = v1;
            p_mbel [(size_t)ct * N + rbase + row] = v2;
        }
    }

    // ---- transpose epilogue (off-diag): same two-phase scheme, 16 partials --
    if (!diag) {
        __syncthreads();               // protect part[] until phase 2 done
        float2 (*tpart)[17] = (float2 (*)[17])smem;   // [col][wr*4+quad], +1 pad
        #pragma unroll
        for (int nt = 0; nt < 4; ++nt) {
            const int c = wc * 64 + nt * 16 + l16;
            const unsigned int pcP1 = ((unsigned int)pg_c[c] & 0xffffu) + 1u;
            const float hpc = hp_c[c];
            float a1 = -BIGF, b1 = -BIGF;
            #pragma unroll
            for (int mt = 0; mt < 2; ++mt) {
                const int4 pr4 = *(const int4*)&pg_r[wr * 32 + mt * 16 + quad * 4];
                float tt0 = (pcP1 != (((unsigned int)pr4.x) >> 16)) ? acc[mt][nt][0] : -BIGF;
                float tt1 = (pcP1 != (((unsigned int)pr4.y) >> 16)) ? acc[mt][nt][1] : -BIGF;
                float tt2 = (pcP1 != (((unsigned int)pr4.z) >> 16)) ? acc[mt][nt][2] : -BIGF;
                float tt3 = (pcP1 != (((unsigned int)pr4.w) >> 16)) ? acc[mt][nt][3] : -BIGF;
                a1 = fmaxf(a1, fmaxf(fmaxf(tt0, tt1), fmaxf(tt2, tt3)));
                float u0 = (tt0 < hpc) ? tt0 : -BIGF;
                float u1 = (tt1 < hpc) ? tt1 : -BIGF;
                float u2 = (tt2 < hpc) ? tt2 : -BIGF;
                float u3 = (tt3 < hpc) ? tt3 : -BIGF;
                b1 = fmaxf(b1, fmaxf(fmaxf(u0, u1), fmaxf(u2, u3)));
            }
            tpart[c][wr * 4 + quad] = float2{a1, b1};
        }
        __syncthreads();
        {
            const int c = t >> 2, sg = t & 3;
            float a = -BIGF, bm = -BIGF;
            #pragma unroll
            for (int k = 0; k < 4; ++k) {
                float2 p = tpart[c][sg * 4 + k];
                a = fmaxf(a, p.x); bm = fmaxf(bm, p.y);
            }
            a  = fmaxf(a,  __shfl_xor(a,  1, 64));
            bm = fmaxf(bm, __shfl_xor(bm, 1, 64));
            a  = fmaxf(a,  __shfl_xor(a,  2, 64));
            bm = fmaxf(bm, __shfl_xor(bm, 2, 64));
            if (sg == 0) {
                p_hnall[(size_t)rt * N + cbase + c] = a;
                p_mbel [(size_t)rt * N + cbase + c] = bm;
            }
        }
    }
}

// ---------------------------------------------------------------------------
// Kernel 4: per-row loss + grid reduce + fused final (parallel version:
// 256 blocks, 32 rows/block, coalesced slot-major reads).
// hn = (mbel > hp - margin) ? mbel : hn_all   (hn_cand == hn_all identity)
// ---------------------------------------------------------------------------
__global__ __launch_bounds__(256) void k_rowloss(
    const float* __restrict__ hp, const float* __restrict__ p_hnall,
    const float* __restrict__ p_mbel, const int* __restrict__ labels,
    float* __restrict__ gred, int* __restrict__ done,
    float* __restrict__ out, int N)
{
    const int t = threadIdx.x;
    const int r = blockIdx.x * 32 + (t & 31);    // row owned by this lane-group
    const int g = t >> 5;                        // slot-group 0..7 (8 slots each)
    float hn_all = -BIGF, mb = -BIGF;
    #pragma unroll
    for (int k = 0; k < 8; ++k) {
        const int s = g * 8 + k;
        hn_all = fmaxf(hn_all, p_hnall[(size_t)s * N + r]);
        mb     = fmaxf(mb,     p_mbel [(size_t)s * N + r]);
    }
    hn_all = fmaxf(hn_all, __shfl_xor(hn_all, 32, 64));
    mb     = fmaxf(mb,     __shfl_xor(mb,     32, 64));
    __shared__ float shn[4][32], smb[4][32];
    const int w = t >> 6, l = t & 63;
    if (l < 32) { shn[w][l] = hn_all; smb[w][l] = mb; }
    __syncthreads();
    if (t < 32) {
        float hn1 = fmaxf(fmaxf(shn[0][t], shn[1][t]), fmaxf(shn[2][t], shn[3][t]));
        float mb1 = fmaxf(fmaxf(smb[0][t], smb[1][t]), fmaxf(smb[2][t], smb[3][t]));
        float hpv = hp[r];
        bool valid = (labels[r] == 1) && (hpv < 1e8f) && (hn1 > -1e8f);
        float hn = (mb1 > hpv - 0.5f) ? mb1 : hn1;
        float base = fmaxf(hn - hpv + 0.5f, 0.f);
        float wgt = (hpv < 0.6f || hn > 0.3f) ? 2.f : 1.f;
        float loss = base * wgt + 0.5f * (1.f - hpv) + 0.5f * fmaxf(hn + 0.2f, 0.f);
        float lsum = valid ? loss : 0.f;
        float lcnt = valid ? 1.f : 0.f;
        #pragma unroll
        for (int off = 16; off >= 1; off >>= 1) {
            lsum += __shfl_xor(lsum, off, 64);
            lcnt += __shfl_xor(lcnt, off, 64);
        }
        if (t == 0) {
            atomicAdd(&gred[0], lsum);
            atomicAdd(&gred[1], lcnt);
            __threadfence();
            int old = atomicAdd(done, 1);
            if (old == (int)gridDim.x - 1) {
                float S = atomicAdd(&gred[0], 0.f);
                float C = atomicAdd(&gred[1], 0.f);
                out[0] = (C > 0.f) ? S / fmaxf(C, 1.f) : 0.f;
            }
        }
    }
}

extern "C" void kernel_launch(void* const* d_in, const int* in_sizes, int n_in,
                              void* d_out, int out_size, void* d_ws, size_t ws_size,
                              hipStream_t stream)
{
    const float* emb = (const float*)d_in[0];
    const int* labels = (const int*)d_in[1];
    const int* pids = (const int*)d_in[2];
    float* out = (float*)d_out;
    int N = in_sizes[1];          // 8192
    int D = in_sizes[0] / N;      // 256

    char* ws = (char*)d_ws;
    unsigned short* normed = (unsigned short*)ws;  ws += (size_t)N * D * 2;  // 4 MB bf16
    int* pg = (int*)ws;                            ws += (size_t)N * 4;
    float* hp = (float*)ws;                        ws += (size_t)N * 4;
    float* p_hnall = (float*)ws;                   ws += (size_t)N * NSLOT * 4;
    float* p_mbel = (float*)ws;                    ws += (size_t)N * NSLOT * 4;
    float* gred = (float*)ws;                      ws += 2 * 4;   // [sum, cnt]
    int* done = (int*)ws;                          ws += 4;

    int M = N / 128;                         // 64 tiles
    int tri = M * (M + 1) / 2;               // 2080 blocks (2016 offdiag + 64 diag)

    k_normalize<<<N / 4, 256, 0, stream>>>(emb, labels, pids, normed, pg, hp,
                                           gred, done);
    k_hp_pid<<<256, 256, 0, stream>>>(normed, labels, pids, hp, N, D);
    k_pass2<<<tri, 512, 0, stream>>>(normed, pg, hp, p_hnall, p_mbel, N);
    k_rowloss<<<N / 32, 256, 0, stream>>>(hp, p_hnall, p_mbel, labels,
                                          gred, done, out, N);
}